// Round 17
// baseline (62.774 us; speedup 1.0000x reference)
//
#include <hip/hip_runtime.h>
#include <stdint.h>

// Fused BSQ: recon = sign(x @ Wp + bp) @ Wr + br   (L2-normalize is sign-invariant)
// x: [65536][512] f32, Wp: [512][16], bp: [16], Wr: [16][512], br: [512]
//
// Round-17 = round-16 + REGISTER PINNING of all weights.
// Evidence: r16 reported VGPR=64 with >=100 live values -> the allocator is
// rematerializing weight loads (re-reading Wp/Wr slices from L2 inside the
// loop) to hit the 64-reg occupancy granule (m68/m69: steps 64/128/256).
// Those reloads are invisible in FETCH_SIZE (L2 hits) but put ~200cyc L2
// latency + extra VMEM on every chunk/recon critical path. Pin via opaque
// asm "+v": the asm result cannot be remat'd, so values stay in VGPRs.
//  - wp pins right after the prologue WAITV(0) (already drained).
//  - wrv/br2v pins right after the first BAR (loads had a half-tile to land).
// Everything else IDENTICAL to r16 (62.3us): 4-slot x 2-row global_load_lds
// ring, counted WAITV(3+k) second half (wr loads oldest -> subsumed), pk-FMA,
// zp[row][d][wave], recon 0..7 interleaved into dots 8..15, nt float2 stores,
// rare (~2%) exact-f64 fixup. Reference signs f64-exact: r1-16 absmax 0.0.

#define ROWS   65536
#define TILE   16
#define BLOCKS (ROWS / TILE)   // 4096
#define TAU    1e-3f

#define BAR()    asm volatile("s_waitcnt lgkmcnt(0)\n\ts_barrier" ::: "memory")
#define WAITV(N) asm volatile("s_waitcnt vmcnt(" #N ")" ::: "memory")
#define WAITL()  asm volatile("s_waitcnt lgkmcnt(0)" ::: "memory")
#define CFENCE() asm volatile("" ::: "memory")
#define PIN(v)   asm volatile("" : "+v"(v))

typedef const __attribute__((address_space(1))) void* gas1_t;
typedef __attribute__((address_space(3))) void*       las3_t;
typedef float v2f __attribute__((ext_vector_type(2)));

__global__ __launch_bounds__(256, 2)
void bsq_fused(const float* __restrict__ x,
               const float* __restrict__ Wp,
               const float* __restrict__ bp,
               const float* __restrict__ Wr,
               const float* __restrict__ br,
               float* __restrict__ out)
{
    const int tid = threadIdx.x;
    const int w   = tid >> 6;      // wave 0..3: c-quarter
    const int l   = tid & 63;
    const int cg  = l >> 4;        // 0..3
    const int dg  = l & 15;        // 0..15: this lane's d

    __shared__ __align__(16) float  xl[4 * 1024];     // 16 KB ring: 4 slots x 2 rows
    __shared__ __align__(16) float  zp[TILE][16][4];  // 4 KB: [row][d][wave]
    __shared__ __align__(16) double zb64[4][16];      // fixup exchange

    // ---- phase-A weights as v2f pairs (issued before the stages) ----
    v2f wpA[8], wpB[8];
#pragma unroll
    for (int j = 0; j < 8; ++j) {
        const float* wj = Wp + (w * 128 + j * 16 + cg * 4) * 16 + dg;
        wpA[j] = (v2f){ wj[0],  wj[16] };
        wpB[j] = (v2f){ wj[32], wj[48] };
    }
    const float bpf = bp[dg];

    const int row0 = blockIdx.x * TILE;
    const float* xsrc = x + (size_t)row0 * 512 + (size_t)(l >> 5) * 512
                          + w * 128 + (l & 31) * 4;

    auto stage = [&](int s) {      // rows 2s,2s+1: wave's 1 KB region, 1 DMA
        __builtin_amdgcn_global_load_lds(
            (gas1_t)(xsrc + (size_t)(2 * s) * 512),
            (las3_t)(&xl[(s & 3) * 1024 + w * 256]), 16, 0, 0);
    };

    auto dot_part = [&](int s, int p, v2f& accA, v2f& accB) {
        const float* bx = &xl[(s & 3) * 1024 + w * 256 + p * 128 + cg * 4];
        float4 xr[8];
#pragma unroll
        for (int j = 0; j < 8; ++j) xr[j] = *(const float4*)(bx + j * 16);
        accA = (v2f){0.f, 0.f};  accB = (v2f){0.f, 0.f};
#pragma unroll
        for (int j = 0; j < 8; ++j) {
            accA += (v2f){ xr[j].x, xr[j].y } * wpA[j];   // v_pk_fma_f32
            accB += (v2f){ xr[j].z, xr[j].w } * wpB[j];
        }
    };
    auto fin_part = [&](int r, v2f accA, v2f accB) {
        float a = (accA.x + accA.y) + (accB.x + accB.y);
        a += __shfl_xor(a, 16, 64);    // reduce over cg (lane bits 4,5)
        a += __shfl_xor(a, 32, 64);
        if (l < 16) zp[r][l][w] = a;   // 2-way bank alias = free
    };

    // ================= prologue: stages + ONE full drain =================
#pragma unroll
    for (int s = 0; s < 4; ++s) stage(s);
    WAITV(0);   // wp/bp + slots 0..3 resident; vm-counting exact from here

    // pin phase-A weights: forbids remat/reload inside the loop
#pragma unroll
    for (int j = 0; j < 8; ++j) { PIN(wpA[j]); PIN(wpB[j]); }

    // ---- phase-B weights NOW (oldest vm ops; subsumed by any later wait) ----
    v2f wrv[16];
    const float2* Wr2 = (const float2*)Wr;
#pragma unroll
    for (int d = 0; d < 16; ++d) {
        const float2 t = Wr2[d * 256 + tid];
        wrv[d] = (v2f){ t.x, t.y };
    }
    const float2 brt = ((const float2*)br)[tid];
    v2f br2v = (v2f){ brt.x, brt.y };
    CFENCE();

    // ========== Phase A first half: rows 0..7 (pure dots) ==========
#pragma unroll 1
    for (int c = 0; c < 4; ++c) {
        v2f aA0, aB0, aA1, aB1;
        dot_part(c, 0, aA0, aB0);      // slot pre-drained, no wait
        dot_part(c, 1, aA1, aB1);
        CFENCE();
        WAITL();                       // slot's ds_reads retired -> reusable
        stage(c + 4);                  // rows 8..15 back into slots 0..3
        CFENCE();
        fin_part(2 * c, aA0, aB0);
        fin_part(2 * c + 1, aA1, aB1);
    }
    BAR();                             // zp rows 0..7 visible (lgkm-only)

    // pin phase-B weights here: their loads had the whole first half to land
#pragma unroll
    for (int d = 0; d < 16; ++d) PIN(wrv[d]);
    PIN(br2v);

    uint32_t amb = 0;                  // block-uniform ambiguity mask
    auto recon_row = [&](int r) {
        const float4 q = *(const float4*)&zp[r][dg][0];   // 1 b128, conflict-free
        const float  z = (q.x + q.y) + (q.z + q.w) + bpf;
        if (__ballot(fabsf(z) < TAU)) amb |= (1u << r);
        const int m = (int)(__ballot(z >= 0.0f) & 0xFFFFull);
        v2f o = br2v;
#pragma unroll
        for (int d = 0; d < 16; ++d) {
            const float s = ((m >> d) & 1) ? 1.0f : -1.0f;
            o += (v2f){ s, s } * wrv[d];                  // v_pk_fma_f32
        }
        __builtin_nontemporal_store(
            o, (v2f*)((float2*)out + (size_t)(row0 + r) * 256 + tid));
    };

    // == Phase A second half (rows 8..15) interleaved with recon rows 0..7 ==
    // Counted waits: before chunk 4+k's dots, newer-than-stage(4+k) =
    // (3-k) stages + 2k stores -> WAITV(3+k). wr loads are older -> covered.
    {
        v2f aA0, aB0, aA1, aB1;
        WAITV(3);
        dot_part(4, 0, aA0, aB0); dot_part(4, 1, aA1, aB1);
        fin_part(8, aA0, aB0); fin_part(9, aA1, aB1);
        recon_row(0); recon_row(1);
        WAITV(4);
        dot_part(5, 0, aA0, aB0); dot_part(5, 1, aA1, aB1);
        fin_part(10, aA0, aB0); fin_part(11, aA1, aB1);
        recon_row(2); recon_row(3);
        WAITV(5);
        dot_part(6, 0, aA0, aB0); dot_part(6, 1, aA1, aB1);
        fin_part(12, aA0, aB0); fin_part(13, aA1, aB1);
        recon_row(4); recon_row(5);
        WAITV(6);
        dot_part(7, 0, aA0, aB0); dot_part(7, 1, aA1, aB1);
        fin_part(14, aA0, aB0); fin_part(15, aA1, aB1);
        recon_row(6); recon_row(7);
    }
    BAR();                             // zp rows 8..15 visible

    // ============ Phase B tail: recon rows 8..15 ============
#pragma unroll 2
    for (int r = 8; r < TILE; ++r) recon_row(r);

    // ===== Fixup: rare exact-f64 redo; uniform loop, matched barriers =====
    const double bpd = (double)bpf;
#pragma unroll 1
    while (amb) {
        const int rr = __ffs(amb) - 1;
        amb &= amb - 1;
        const int row = row0 + rr;

        const float* xp = x + (size_t)row * 512 + w * 128 + cg * 4;
        double ad = 0.0;
#pragma unroll
        for (int j = 0; j < 8; ++j) {
            const float4 xf = *(const float4*)(xp + j * 16);
#pragma unroll
            for (int e = 0; e < 4; ++e) {
                const float wpe = Wp[(w * 128 + j * 16 + cg * 4 + e) * 16 + dg];
                const float xe  = e == 0 ? xf.x : e == 1 ? xf.y
                               : e == 2 ? xf.z : xf.w;
                ad = fma((double)xe, (double)wpe, ad);
            }
        }
        ad += __shfl_xor(ad, 16, 64);
        ad += __shfl_xor(ad, 32, 64);
        if (l < 16) zb64[w][l] = ad;
        BAR();
        const double zd = (zb64[0][dg] + zb64[1][dg])
                        + (zb64[2][dg] + zb64[3][dg]) + bpd;
        const int m = (int)(__ballot(zd >= 0.0) & 0xFFFFull);
        BAR();   // zb64 reads retired before next fixup row's rewrite

        v2f o = br2v;
#pragma unroll
        for (int d = 0; d < 16; ++d) {
            const float s = ((m >> d) & 1) ? 1.0f : -1.0f;
            o += (v2f){ s, s } * wrv[d];
        }
        __builtin_nontemporal_store(
            o, (v2f*)((float2*)out + (size_t)row * 256 + tid));
    }
}

extern "C" void kernel_launch(void* const* d_in, const int* in_sizes, int n_in,
                              void* d_out, int out_size, void* d_ws, size_t ws_size,
                              hipStream_t stream) {
    const float* x  = (const float*)d_in[0];
    const float* Wp = (const float*)d_in[1];
    const float* bp = (const float*)d_in[2];
    const float* Wr = (const float*)d_in[3];
    const float* br = (const float*)d_in[4];
    float* out = (float*)d_out;

    bsq_fused<<<BLOCKS, 256, 0, stream>>>(x, Wp, bp, Wr, br, out);
}

// Round 18
// 61.244 us; speedup vs baseline: 1.0250x; 1.0250x over previous
//
#include <hip/hip_runtime.h>
#include <stdint.h>

// Fused BSQ: recon = sign(x @ Wp + bp) @ Wr + br   (L2-normalize is sign-invariant)
// x: [65536][512] f32, Wp: [512][16], bp: [16], Wr: [16][512], br: [512]
//
// Round-18 = round-16 with the 4-slot ring replaced by WHOLE-TILE staging:
//  - 8 slots x 2 rows = all 16 rows DMA'd at block start (max prefetch depth
//    ~2500+ cyc vs the ring's ~500 - the residual per-chunk WAITV stall).
//  - No slot reuse -> the per-chunk WAITL (lgkm fence) disappears.
//  - Weights (wp, wr, br, bp) load BEFORE the stages (oldest in vm queue),
//    drained by one WAITV(8); chunks consume with countdown WAITV(7-c);
//    second half identical counted waits to r16 (3,4,5,6: stores replace
//    stages one-for-one in the in-order queue).
//  - Everything else identical to r16 (62.3us): pk-FMA dot, 2-shuffle
//    cg-reduce, zp[row][d][wave], recon rows 0..7 interleaved into dot-chunks
//    of rows 8..15, nt float2 stores, block-uniform ambiguity mask, rare
//    (~2%) exact-f64 fixup. Reference signs f64-exact: r1-17 absmax 0.0.

#define ROWS   65536
#define TILE   16
#define BLOCKS (ROWS / TILE)   // 4096
#define TAU    1e-3f

#define BAR()    asm volatile("s_waitcnt lgkmcnt(0)\n\ts_barrier" ::: "memory")
#define WAITV(N) asm volatile("s_waitcnt vmcnt(" #N ")" ::: "memory")
#define CFENCE() asm volatile("" ::: "memory")

typedef const __attribute__((address_space(1))) void* gas1_t;
typedef __attribute__((address_space(3))) void*       las3_t;
typedef float v2f __attribute__((ext_vector_type(2)));

__global__ __launch_bounds__(256, 2)
void bsq_fused(const float* __restrict__ x,
               const float* __restrict__ Wp,
               const float* __restrict__ bp,
               const float* __restrict__ Wr,
               const float* __restrict__ br,
               float* __restrict__ out)
{
    const int tid = threadIdx.x;
    const int w   = tid >> 6;      // wave 0..3: c-quarter
    const int l   = tid & 63;
    const int cg  = l >> 4;        // 0..3
    const int dg  = l & 15;        // 0..15: this lane's d

    __shared__ __align__(16) float  xl[8 * 1024];     // 32 KB: whole tile
    __shared__ __align__(16) float  zp[TILE][16][4];  // 4 KB: [row][d][wave]
    __shared__ __align__(16) double zb64[4][16];      // fixup exchange

    // ---- ALL weights first: oldest vm ops, drained by the single WAITV(8) ----
    v2f wpA[8], wpB[8];
#pragma unroll
    for (int j = 0; j < 8; ++j) {
        const float* wj = Wp + (w * 128 + j * 16 + cg * 4) * 16 + dg;
        wpA[j] = (v2f){ wj[0],  wj[16] };
        wpB[j] = (v2f){ wj[32], wj[48] };
    }
    const float bpf = bp[dg];
    v2f wrv[16];
    const float2* Wr2 = (const float2*)Wr;
#pragma unroll
    for (int d = 0; d < 16; ++d) {
        const float2 t = Wr2[d * 256 + tid];
        wrv[d] = (v2f){ t.x, t.y };
    }
    const float2 brt = ((const float2*)br)[tid];
    const v2f br2v = (v2f){ brt.x, brt.y };
    CFENCE();

    const int row0 = blockIdx.x * TILE;
    const float* xsrc = x + (size_t)row0 * 512 + (size_t)(l >> 5) * 512
                          + w * 128 + (l & 31) * 4;

    auto stage = [&](int s) {      // rows 2s,2s+1: wave's 1 KB region, 1 DMA
        __builtin_amdgcn_global_load_lds(
            (gas1_t)(xsrc + (size_t)(2 * s) * 512),
            (las3_t)(&xl[s * 1024 + w * 256]), 16, 0, 0);
    };

    auto dot_part = [&](int s, int p, v2f& accA, v2f& accB) {
        const float* bx = &xl[s * 1024 + w * 256 + p * 128 + cg * 4];
        float4 xr[8];
#pragma unroll
        for (int j = 0; j < 8; ++j) xr[j] = *(const float4*)(bx + j * 16);
        accA = (v2f){0.f, 0.f};  accB = (v2f){0.f, 0.f};
#pragma unroll
        for (int j = 0; j < 8; ++j) {
            accA += (v2f){ xr[j].x, xr[j].y } * wpA[j];   // v_pk_fma_f32
            accB += (v2f){ xr[j].z, xr[j].w } * wpB[j];
        }
    };
    auto fin_part = [&](int r, v2f accA, v2f accB) {
        float a = (accA.x + accA.y) + (accB.x + accB.y);
        a += __shfl_xor(a, 16, 64);    // reduce over cg (lane bits 4,5)
        a += __shfl_xor(a, 32, 64);
        if (l < 16) zp[r][l][w] = a;   // 2-way bank alias = free
    };

    // ============ prologue: stage the WHOLE tile, drain weights ============
#pragma unroll
    for (int s = 0; s < 8; ++s) stage(s);
    WAITV(8);   // all weight loads retired; 8 stages outstanding
    CFENCE();

    // ========== Phase A first half: rows 0..7, countdown waits ==========
    {
        v2f aA0, aB0, aA1, aB1;
        WAITV(7); dot_part(0, 0, aA0, aB0); dot_part(0, 1, aA1, aB1);
        fin_part(0, aA0, aB0); fin_part(1, aA1, aB1);
        WAITV(6); dot_part(1, 0, aA0, aB0); dot_part(1, 1, aA1, aB1);
        fin_part(2, aA0, aB0); fin_part(3, aA1, aB1);
        WAITV(5); dot_part(2, 0, aA0, aB0); dot_part(2, 1, aA1, aB1);
        fin_part(4, aA0, aB0); fin_part(5, aA1, aB1);
        WAITV(4); dot_part(3, 0, aA0, aB0); dot_part(3, 1, aA1, aB1);
        fin_part(6, aA0, aB0); fin_part(7, aA1, aB1);
    }
    BAR();                             // zp rows 0..7 visible (lgkm-only)

    uint32_t amb = 0;                  // block-uniform ambiguity mask
    auto recon_row = [&](int r) {
        const float4 q = *(const float4*)&zp[r][dg][0];   // 1 b128, conflict-free
        const float  z = (q.x + q.y) + (q.z + q.w) + bpf;
        if (__ballot(fabsf(z) < TAU)) amb |= (1u << r);
        const int m = (int)(__ballot(z >= 0.0f) & 0xFFFFull);
        v2f o = br2v;
#pragma unroll
        for (int d = 0; d < 16; ++d) {
            const float s = ((m >> d) & 1) ? 1.0f : -1.0f;
            o += (v2f){ s, s } * wrv[d];                  // v_pk_fma_f32
        }
        __builtin_nontemporal_store(
            o, (v2f*)((float2*)out + (size_t)(row0 + r) * 256 + tid));
    };

    // == Phase A second half (rows 8..15) interleaved with recon rows 0..7 ==
    // Before chunk 4+k: newer-than-stage(4+k) = (3-k) stages + 2k stores
    // -> WAITV(3+k), identical counts to r16 (stores swap in for stages).
    {
        v2f aA0, aB0, aA1, aB1;
        WAITV(3);
        dot_part(4, 0, aA0, aB0); dot_part(4, 1, aA1, aB1);
        fin_part(8, aA0, aB0); fin_part(9, aA1, aB1);
        recon_row(0); recon_row(1);
        WAITV(4);
        dot_part(5, 0, aA0, aB0); dot_part(5, 1, aA1, aB1);
        fin_part(10, aA0, aB0); fin_part(11, aA1, aB1);
        recon_row(2); recon_row(3);
        WAITV(5);
        dot_part(6, 0, aA0, aB0); dot_part(6, 1, aA1, aB1);
        fin_part(12, aA0, aB0); fin_part(13, aA1, aB1);
        recon_row(4); recon_row(5);
        WAITV(6);
        dot_part(7, 0, aA0, aB0); dot_part(7, 1, aA1, aB1);
        fin_part(14, aA0, aB0); fin_part(15, aA1, aB1);
        recon_row(6); recon_row(7);
    }
    BAR();                             // zp rows 8..15 visible

    // ============ Phase B tail: recon rows 8..15 ============
#pragma unroll 2
    for (int r = 8; r < TILE; ++r) recon_row(r);

    // ===== Fixup: rare exact-f64 redo; uniform loop, matched barriers =====
    const double bpd = (double)bpf;
#pragma unroll 1
    while (amb) {
        const int rr = __ffs(amb) - 1;
        amb &= amb - 1;
        const int row = row0 + rr;

        const float* xp = x + (size_t)row * 512 + w * 128 + cg * 4;
        double ad = 0.0;
#pragma unroll
        for (int j = 0; j < 8; ++j) {
            const float4 xf = *(const float4*)(xp + j * 16);
#pragma unroll
            for (int e = 0; e < 4; ++e) {
                const float wpe = Wp[(w * 128 + j * 16 + cg * 4 + e) * 16 + dg];
                const float xe  = e == 0 ? xf.x : e == 1 ? xf.y
                               : e == 2 ? xf.z : xf.w;
                ad = fma((double)xe, (double)wpe, ad);
            }
        }
        ad += __shfl_xor(ad, 16, 64);
        ad += __shfl_xor(ad, 32, 64);
        if (l < 16) zb64[w][l] = ad;
        BAR();
        const double zd = (zb64[0][dg] + zb64[1][dg])
                        + (zb64[2][dg] + zb64[3][dg]) + bpd;
        const int m = (int)(__ballot(zd >= 0.0) & 0xFFFFull);
        BAR();   // zb64 reads retired before next fixup row's rewrite

        v2f o = br2v;
#pragma unroll
        for (int d = 0; d < 16; ++d) {
            const float s = ((m >> d) & 1) ? 1.0f : -1.0f;
            o += (v2f){ s, s } * wrv[d];
        }
        __builtin_nontemporal_store(
            o, (v2f*)((float2*)out + (size_t)row * 256 + tid));
    }
}

extern "C" void kernel_launch(void* const* d_in, const int* in_sizes, int n_in,
                              void* d_out, int out_size, void* d_ws, size_t ws_size,
                              hipStream_t stream) {
    const float* x  = (const float*)d_in[0];
    const float* Wp = (const float*)d_in[1];
    const float* bp = (const float*)d_in[2];
    const float* Wr = (const float*)d_in[3];
    const float* br = (const float*)d_in[4];
    float* out = (float*)d_out;

    bsq_fused<<<BLOCKS, 256, 0, stream>>>(x, Wp, bp, Wr, br, out);
}